// Round 5
// baseline (297.716 us; speedup 1.0000x reference)
//
#include <hip/hip_runtime.h>
#include <hip/hip_bf16.h>

// Problem constants
#define BB 16
#define TT 2048
#define CC 128
#define HH 128
#define NQT128 16          // q tiles of 128 rows

typedef __bf16 bf16x8 __attribute__((ext_vector_type(8)));
typedef float  f32x4  __attribute__((ext_vector_type(4)));

// ws layout (bf16 elems unless noted):
//   Qs  [b][tt16 128][ks 4][lane 64][j 8]   (exp2-domain scale folded)
//   Ks  [b][tt16 128][ks 4][lane 64][j 8]
//   Vs  [b][t32 64][h16 8][lane 64][j 8]
//   Wbf 3*128*128  (Wq pre-scaled)
//   partials (float): slots of [128*128 o + 128 l]
#define BTH       ((size_t)BB * TT * HH)
#define WBF_OFF   (3 * BTH)
#define PARTIAL_OFF_BYTES (3 * BTH * 2 + 3 * 128 * 128 * 2)
#define SLOT_FLOATS (128 * 128 + 128)     // 16512

static __device__ __forceinline__ bf16x8 load_cvt8(const float* __restrict__ p) {
    float4 a = *(const float4*)p;
    float4 b = *(const float4*)(p + 4);
    bf16x8 r;
    r[0] = (__bf16)a.x; r[1] = (__bf16)a.y; r[2] = (__bf16)a.z; r[3] = (__bf16)a.w;
    r[4] = (__bf16)b.x; r[5] = (__bf16)b.y; r[6] = (__bf16)b.z; r[7] = (__bf16)b.w;
    return r;
}

// ---------------------------------------------------------------------------
// W pre-convert: fp32 -> bf16, Wq scaled by C^-0.5 * log2e.
// ---------------------------------------------------------------------------
__global__ __launch_bounds__(256) void wcvt_kernel(
    const float* __restrict__ Wq, const float* __restrict__ Wk,
    const float* __restrict__ Wv, __bf16* __restrict__ wbf)
{
    int idx = blockIdx.x * 256 + threadIdx.x;          // < 49152
    int m = idx >> 14;
    int e = idx & 16383;
    const float* src = (m == 0) ? Wq : (m == 1) ? Wk : Wv;
    float sc = (m == 0) ? (0.08838834764831845f * 1.4426950408889634f) : 1.0f;
    wbf[idx] = (__bf16)(src[e] * sc);
}

// ---------------------------------------------------------------------------
// Projection with fragment-swizzled output. grid 512, block 256 (4 waves).
// ---------------------------------------------------------------------------
#define TR_QK 132
#define TR_V  68

__global__ __launch_bounds__(256) void proj_kernel(
    const float* __restrict__ x, __bf16* __restrict__ ws)
{
    __shared__ __bf16 tr[128 * TR_V];

    const int lane = threadIdx.x & 63;
    const int wave = threadIdx.x >> 6;
    const int quad = lane >> 4;
    const int l16  = lane & 15;
    const int m0 = blockIdx.x * 64;
    const int b  = m0 / TT;
    const int t0 = m0 % TT;

    const __bf16* Wbf = ws + WBF_OFF;
    __bf16* Qs = ws;
    __bf16* Ks = ws + BTH;
    __bf16* Vs = ws + 2 * BTH;

    bf16x8 xf[4];
    #pragma unroll
    for (int ks = 0; ks < 4; ++ks)
        xf[ks] = load_cvt8(x + (size_t)(m0 + wave * 16 + l16) * CC + ks * 32 + quad * 8);

    #pragma unroll
    for (int which = 0; which < 2; ++which) {
        const __bf16* Wb = Wbf + (size_t)which * (128 * 128);
        __bf16* dst = which ? Ks : Qs;
        #pragma unroll
        for (int nt = 0; nt < 8; ++nt) {
            f32x4 acc = {0.f, 0.f, 0.f, 0.f};
            #pragma unroll
            for (int ks = 0; ks < 4; ++ks) {
                bf16x8 wf = *(const bf16x8*)(Wb + (size_t)(nt * 16 + l16) * CC + ks * 32 + quad * 8);
                acc = __builtin_amdgcn_mfma_f32_16x16x32_bf16(xf[ks], wf, acc, 0, 0, 0);
            }
            #pragma unroll
            for (int r = 0; r < 4; ++r)
                tr[(wave * 16 + quad * 4 + r) * TR_QK + nt * 16 + l16] = (__bf16)acc[r];
        }
        asm volatile("s_waitcnt lgkmcnt(0)" ::: "memory");
        #pragma unroll
        for (int ks = 0; ks < 4; ++ks) {
            const __bf16* p = &tr[(wave * 16 + l16) * TR_QK + ks * 32 + quad * 8];
            uint2 lo = *(const uint2*)p;
            uint2 hi = *(const uint2*)(p + 4);
            uint4 v; v.x = lo.x; v.y = lo.y; v.z = hi.x; v.w = hi.y;
            __bf16* o = dst + (((size_t)(b * 128 + t0 / 16 + wave) * 4 + ks) << 9) + lane * 8;
            *(uint4*)o = v;
        }
        asm volatile("s_waitcnt lgkmcnt(0)" ::: "memory");
    }

    __syncthreads();
    const __bf16* Wv = Wbf + 2 * (128 * 128);
    #pragma unroll
    for (int msub = 0; msub < 8; ++msub) {
        f32x4 acc = {0.f, 0.f, 0.f, 0.f};
        #pragma unroll
        for (int ks = 0; ks < 4; ++ks) {
            bf16x8 wf = *(const bf16x8*)(Wv + (size_t)(msub * 16 + l16) * CC + ks * 32 + quad * 8);
            acc = __builtin_amdgcn_mfma_f32_16x16x32_bf16(wf, xf[ks], acc, 0, 0, 0);
        }
        #pragma unroll
        for (int r = 0; r < 4; ++r)
            tr[(msub * 16 + quad * 4 + r) * TR_V + wave * 16 + l16] = (__bf16)acc[r];
    }
    __syncthreads();
    #pragma unroll
    for (int i = 0; i < 4; ++i) {
        int t32 = i >> 1;
        int h16 = wave * 2 + (i & 1);
        const __bf16* p = &tr[(h16 * 16 + l16) * TR_V + t32 * 32 + quad * 8];
        uint2 lo = *(const uint2*)p;
        uint2 hi = *(const uint2*)(p + 4);
        uint4 v; v.x = lo.x; v.y = lo.y; v.z = hi.x; v.w = hi.y;
        __bf16* o = Vs + (((size_t)(b * 64 + t0 / 32 + t32) * 8 + h16) << 9) + lane * 8;
        *(uint4*)o = v;
    }
}

// ---------------------------------------------------------------------------
// Split-K flash attention, 128 q-rows/block, 32 q-rows/wave (2 subtiles).
// grid (SPB, 16), block 256 (4 waves). Static-max softmax (p = exp2(s-16)).
// Per-wave causal clamp skips fully-masked key tiles. All global loads are
// wave-uniform base + lane*16B (fragment-swizzled inputs).
// ---------------------------------------------------------------------------
#define S_LDS 76
#define EXP_BIAS 16.0f

__global__ __launch_bounds__(256) void attn_kernel(
    const __bf16* __restrict__ ws, float* __restrict__ po,
    float* __restrict__ outp, int G, int SPB, int direct)
{
    __shared__ __bf16 lds_p[4 * 32 * S_LDS];

    const int lane = threadIdx.x & 63;
    const int wave = threadIdx.x >> 6;
    const int quad = lane >> 4;
    const int l16  = lane & 15;
    const int lane8 = lane * 8;

    const int b = blockIdx.y;
    const int s = SPB - 1 - blockIdx.x;

    // slot -> (qt, seg)
    int acc = 0, qt = 0, seg = 0;
    for (int q = 0; q < NQT128; ++q) {
        int c = (2 * (q + 1) + G - 1) / G;
        if (s < acc + c) { qt = q; seg = s - acc; break; }
        acc += c;
    }
    const int kt0 = seg * G;
    int kt1 = 2 * (qt + 1);
    if (kt0 + G < kt1) kt1 = kt0 + G;

    const int q0 = qt * 128;
    const int qw = q0 + wave * 32;                 // wave's first q row
    int kt1w = (qw + 32 + 63) >> 6;                // wave causal clamp (excl)
    if (kt1w > kt1) kt1w = kt1;

    const __bf16* Qs = ws;
    const __bf16* Ks = ws + BTH;
    const __bf16* Vs = ws + 2 * BTH;

    bf16x8 qf[2][4];
    #pragma unroll
    for (int m = 0; m < 2; ++m)
        #pragma unroll
        for (int ks = 0; ks < 4; ++ks)
            qf[m][ks] = *(const bf16x8*)(Qs + (((size_t)(b * 128 + qt * 8 + wave * 2 + m) * 4 + ks) << 9) + lane8);

    float l_r[2][4];
    f32x4 o[2][8];
    #pragma unroll
    for (int m = 0; m < 2; ++m) {
        #pragma unroll
        for (int r = 0; r < 4; ++r) l_r[m][r] = 0.f;
        #pragma unroll
        for (int h8 = 0; h8 < 8; ++h8) o[m][h8] = (f32x4){0.f, 0.f, 0.f, 0.f};
    }

    __bf16* myP = lds_p + wave * 32 * S_LDS;

    // prologue: K fragments for first tile
    bf16x8 kf[4][4];
    #pragma unroll
    for (int nsub = 0; nsub < 4; ++nsub)
        #pragma unroll
        for (int ks = 0; ks < 4; ++ks)
            kf[nsub][ks] = *(const bf16x8*)(Ks + (((size_t)(b * 128 + kt0 * 4 + nsub) * 4 + ks) << 9) + lane8);

    for (int kt = kt0; kt < kt1w; ++kt) {
        const int k0 = kt * 64;

        // V half 0 (h8 = 0..3, both 32-key chunks) issued early
        bf16x8 va[4], vb[4];
        #pragma unroll
        for (int h8 = 0; h8 < 4; ++h8) {
            va[h8] = *(const bf16x8*)(Vs + (((size_t)(b * 64 + kt * 2 + 0) * 8 + h8) << 9) + lane8);
            vb[h8] = *(const bf16x8*)(Vs + (((size_t)(b * 64 + kt * 2 + 1) * 8 + h8) << 9) + lane8);
        }

        // S = Q K^T for both subtiles (independent chains)
        f32x4 s2[2][4];
        #pragma unroll
        for (int m = 0; m < 2; ++m)
            #pragma unroll
            for (int nsub = 0; nsub < 4; ++nsub) {
                f32x4 a2 = {0.f, 0.f, 0.f, 0.f};
                #pragma unroll
                for (int ks = 0; ks < 4; ++ks)
                    a2 = __builtin_amdgcn_mfma_f32_16x16x32_bf16(qf[m][ks], kf[nsub][ks], a2, 0, 0, 0);
                s2[m][nsub] = a2;
            }

        // prefetch next K tile in place
        const int ktn = (kt + 1 < kt1w) ? (kt + 1) : kt;
        #pragma unroll
        for (int nsub = 0; nsub < 4; ++nsub)
            #pragma unroll
            for (int ks = 0; ks < 4; ++ks)
                kf[nsub][ks] = *(const bf16x8*)(Ks + (((size_t)(b * 128 + ktn * 4 + nsub) * 4 + ks) << 9) + lane8);

        // mask + exp2 + lane-local l + LDS write
        #pragma unroll
        for (int m = 0; m < 2; ++m) {
            const int qr0m = qw + m * 16;
            if (k0 + 63 > qr0m) {
                #pragma unroll
                for (int nsub = 0; nsub < 4; ++nsub) {
                    int key = k0 + nsub * 16 + l16;
                    #pragma unroll
                    for (int r = 0; r < 4; ++r) {
                        int rowq = qr0m + quad * 4 + r;
                        if (key > rowq) s2[m][nsub][r] = -3e38f;
                    }
                }
            }
            #pragma unroll
            for (int nsub = 0; nsub < 4; ++nsub) {
                #pragma unroll
                for (int r = 0; r < 4; ++r) {
                    float p = __builtin_amdgcn_exp2f(s2[m][nsub][r] - EXP_BIAS);
                    l_r[m][r] += p;
                    myP[(m * 16 + quad * 4 + r) * S_LDS + nsub * 16 + l16] = (__bf16)p;
                }
            }
        }
        asm volatile("s_waitcnt lgkmcnt(0)" ::: "memory");

        // P: C-layout -> A-layout for both subtiles
        bf16x8 pf[2][2];
        #pragma unroll
        for (int m = 0; m < 2; ++m)
            #pragma unroll
            for (int ks2 = 0; ks2 < 2; ++ks2) {
                union { bf16x8 v; uint2 h[2]; } u;
                const char* base = (const char*)myP + (size_t)(m * 16 + l16) * (S_LDS * 2) + ks2 * 64 + quad * 16;
                u.h[0] = *(const uint2*)base;
                u.h[1] = *(const uint2*)(base + 8);
                pf[m][ks2] = u.v;
            }

        // O += P V
        #pragma unroll
        for (int h8 = 0; h8 < 4; ++h8)
            #pragma unroll
            for (int m = 0; m < 2; ++m) {
                o[m][h8] = __builtin_amdgcn_mfma_f32_16x16x32_bf16(pf[m][0], va[h8], o[m][h8], 0, 0, 0);
                o[m][h8] = __builtin_amdgcn_mfma_f32_16x16x32_bf16(pf[m][1], vb[h8], o[m][h8], 0, 0, 0);
            }
        #pragma unroll
        for (int h8 = 4; h8 < 8; ++h8) {
            bf16x8 v0 = *(const bf16x8*)(Vs + (((size_t)(b * 64 + kt * 2 + 0) * 8 + h8) << 9) + lane8);
            bf16x8 v1 = *(const bf16x8*)(Vs + (((size_t)(b * 64 + kt * 2 + 1) * 8 + h8) << 9) + lane8);
            #pragma unroll
            for (int m = 0; m < 2; ++m) {
                o[m][h8] = __builtin_amdgcn_mfma_f32_16x16x32_bf16(pf[m][0], v0, o[m][h8], 0, 0, 0);
                o[m][h8] = __builtin_amdgcn_mfma_f32_16x16x32_bf16(pf[m][1], v1, o[m][h8], 0, 0, 0);
            }
        }
    }

    // l reduction across the 16-lane row group
    #pragma unroll
    for (int m = 0; m < 2; ++m)
        #pragma unroll
        for (int r = 0; r < 4; ++r)
            #pragma unroll
            for (int j = 1; j <= 8; j <<= 1)
                l_r[m][r] += __shfl_xor(l_r[m][r], j, 64);

    if (direct) {
        #pragma unroll
        for (int m = 0; m < 2; ++m) {
            float inv[4];
            #pragma unroll
            for (int r = 0; r < 4; ++r) inv[r] = 1.0f / l_r[m][r];
            #pragma unroll
            for (int h8 = 0; h8 < 8; ++h8)
                #pragma unroll
                for (int r = 0; r < 4; ++r)
                    outp[(size_t)(b * TT + qw + m * 16 + quad * 4 + r) * HH + h8 * 16 + l16] = o[m][h8][r] * inv[r];
        }
    } else {
        float* slot = po + (size_t)(b * SPB + s) * SLOT_FLOATS;
        #pragma unroll
        for (int m = 0; m < 2; ++m) {
            #pragma unroll
            for (int h8 = 0; h8 < 8; ++h8)
                #pragma unroll
                for (int r = 0; r < 4; ++r)
                    slot[(size_t)(wave * 32 + m * 16 + quad * 4 + r) * HH + h8 * 16 + l16] = o[m][h8][r];
            if (l16 == 0) {
                #pragma unroll
                for (int r = 0; r < 4; ++r)
                    slot[128 * 128 + wave * 32 + m * 16 + quad * 4 + r] = l_r[m][r];
            }
        }
    }
}

// ---------------------------------------------------------------------------
// Reduce: sum partial (o, l) over segments, normalize. grid (16, 16), 256 thr.
// ---------------------------------------------------------------------------
__global__ __launch_bounds__(256) void reduce_kernel(
    const float* __restrict__ po, float* __restrict__ outp, int G, int SPB)
{
    __shared__ float lsum[128];
    const int q = blockIdx.x;
    const int b = blockIdx.y;
    const int tid = threadIdx.x;

    int acc = 0;
    for (int qq = 0; qq < q; ++qq) acc += (2 * (qq + 1) + G - 1) / G;
    const int segs = (2 * (q + 1) + G - 1) / G;
    const float* base = po + (size_t)(b * SPB + acc) * SLOT_FLOATS;

    if (tid < 128) {
        float v = 0.f;
        for (int sg = 0; sg < segs; ++sg)
            v += base[(size_t)sg * SLOT_FLOATS + 128 * 128 + tid];
        lsum[tid] = v;
    }
    __syncthreads();

    const int col = tid & 127;
    const int rh  = tid >> 7;
    for (int i = 0; i < 64; ++i) {
        int rowl = rh * 64 + i;
        float a = 0.f;
        for (int sg = 0; sg < segs; ++sg)
            a += base[(size_t)sg * SLOT_FLOATS + (size_t)rowl * 128 + col];
        outp[(size_t)(b * TT + q * 128 + rowl) * HH + col] = a / lsum[rowl];
    }
}

extern "C" void kernel_launch(void* const* d_in, const int* in_sizes, int n_in,
                              void* d_out, int out_size, void* d_ws, size_t ws_size,
                              hipStream_t stream)
{
    const float* x  = (const float*)d_in[0];
    const float* Wq = (const float*)d_in[1];
    const float* Wk = (const float*)d_in[2];
    const float* Wv = (const float*)d_in[3];
    __bf16* ws = (__bf16*)d_ws;
    float* out = (float*)d_out;
    float* po  = (float*)((char*)d_ws + PARTIAL_OFF_BYTES);

    int G = 0, SPB = 0, direct = 1;
    const int cand[3] = {4, 8, 16};
    for (int ci = 0; ci < 3; ++ci) {
        int g = cand[ci], spb = 0;
        for (int q = 0; q < NQT128; ++q) spb += (2 * (q + 1) + g - 1) / g;
        size_t need = PARTIAL_OFF_BYTES + (size_t)spb * BB * SLOT_FLOATS * 4;
        if (need <= ws_size) { G = g; SPB = spb; direct = 0; break; }
    }
    if (direct) { G = 2 * NQT128; SPB = NQT128; }   // one segment per qtile

    wcvt_kernel<<<192, 256, 0, stream>>>(Wq, Wk, Wv, ws + WBF_OFF);
    proj_kernel<<<512, 256, 0, stream>>>(x, ws);
    dim3 agrid(SPB, BB);
    attn_kernel<<<agrid, 256, 0, stream>>>(ws, po, out, G, SPB, direct);
    if (!direct) {
        dim3 rgrid(NQT128, BB);
        reduce_kernel<<<rgrid, 256, 0, stream>>>(po, out, G, SPB);
    }
}

// Round 6
// 176.123 us; speedup vs baseline: 1.6904x; 1.6904x over previous
//
#include <hip/hip_runtime.h>
#include <hip/hip_bf16.h>

// Problem constants
#define BB 16
#define TT 2048
#define CC 128
#define HH 128
#define NQT128 16          // q tiles of 128 rows

typedef __bf16 bf16x8 __attribute__((ext_vector_type(8)));
typedef float  f32x4  __attribute__((ext_vector_type(4)));

// ws layout (bf16 elems unless noted):
//   Qs  [b][tt16 128][ks 4][lane 64][j 8]   (exp2-domain scale folded)
//   Ks  [b][tt16 128][ks 4][lane 64][j 8]
//   Vs  [b][t32 64][h16 8][lane 64][j 8]
//   Wbf 3*128*128  (Wq pre-scaled)
//   partials (float): slots of [128*128 o + 128 l]
#define BTH       ((size_t)BB * TT * HH)
#define WBF_OFF   (3 * BTH)
#define PARTIAL_OFF_BYTES (3 * BTH * 2 + 3 * 128 * 128 * 2)
#define SLOT_FLOATS (128 * 128 + 128)     // 16512

static __device__ __forceinline__ bf16x8 load_cvt8(const float* __restrict__ p) {
    float4 a = *(const float4*)p;
    float4 b = *(const float4*)(p + 4);
    bf16x8 r;
    r[0] = (__bf16)a.x; r[1] = (__bf16)a.y; r[2] = (__bf16)a.z; r[3] = (__bf16)a.w;
    r[4] = (__bf16)b.x; r[5] = (__bf16)b.y; r[6] = (__bf16)b.z; r[7] = (__bf16)b.w;
    return r;
}

// ---------------------------------------------------------------------------
// W pre-convert: fp32 -> bf16, Wq scaled by C^-0.5 * log2e.
// ---------------------------------------------------------------------------
__global__ __launch_bounds__(256) void wcvt_kernel(
    const float* __restrict__ Wq, const float* __restrict__ Wk,
    const float* __restrict__ Wv, __bf16* __restrict__ wbf)
{
    int idx = blockIdx.x * 256 + threadIdx.x;          // < 49152
    int m = idx >> 14;
    int e = idx & 16383;
    const float* src = (m == 0) ? Wq : (m == 1) ? Wk : Wv;
    float sc = (m == 0) ? (0.08838834764831845f * 1.4426950408889634f) : 1.0f;
    wbf[idx] = (__bf16)(src[e] * sc);
}

// ---------------------------------------------------------------------------
// Projection with fragment-swizzled output. grid 512, block 256 (4 waves).
// ---------------------------------------------------------------------------
#define TR_QK 132
#define TR_V  68

__global__ __launch_bounds__(256) void proj_kernel(
    const float* __restrict__ x, __bf16* __restrict__ ws)
{
    __shared__ __bf16 tr[128 * TR_V];

    const int lane = threadIdx.x & 63;
    const int wave = threadIdx.x >> 6;
    const int quad = lane >> 4;
    const int l16  = lane & 15;
    const int m0 = blockIdx.x * 64;
    const int b  = m0 / TT;
    const int t0 = m0 % TT;

    const __bf16* Wbf = ws + WBF_OFF;
    __bf16* Qs = ws;
    __bf16* Ks = ws + BTH;
    __bf16* Vs = ws + 2 * BTH;

    bf16x8 xf[4];
    #pragma unroll
    for (int ks = 0; ks < 4; ++ks)
        xf[ks] = load_cvt8(x + (size_t)(m0 + wave * 16 + l16) * CC + ks * 32 + quad * 8);

    #pragma unroll
    for (int which = 0; which < 2; ++which) {
        const __bf16* Wb = Wbf + (size_t)which * (128 * 128);
        __bf16* dst = which ? Ks : Qs;
        #pragma unroll
        for (int nt = 0; nt < 8; ++nt) {
            f32x4 acc = {0.f, 0.f, 0.f, 0.f};
            #pragma unroll
            for (int ks = 0; ks < 4; ++ks) {
                bf16x8 wf = *(const bf16x8*)(Wb + (size_t)(nt * 16 + l16) * CC + ks * 32 + quad * 8);
                acc = __builtin_amdgcn_mfma_f32_16x16x32_bf16(xf[ks], wf, acc, 0, 0, 0);
            }
            #pragma unroll
            for (int r = 0; r < 4; ++r)
                tr[(wave * 16 + quad * 4 + r) * TR_QK + nt * 16 + l16] = (__bf16)acc[r];
        }
        asm volatile("s_waitcnt lgkmcnt(0)" ::: "memory");
        #pragma unroll
        for (int ks = 0; ks < 4; ++ks) {
            const __bf16* p = &tr[(wave * 16 + l16) * TR_QK + ks * 32 + quad * 8];
            uint2 lo = *(const uint2*)p;
            uint2 hi = *(const uint2*)(p + 4);
            uint4 v; v.x = lo.x; v.y = lo.y; v.z = hi.x; v.w = hi.y;
            __bf16* o = dst + (((size_t)(b * 128 + t0 / 16 + wave) * 4 + ks) << 9) + lane * 8;
            *(uint4*)o = v;
        }
        asm volatile("s_waitcnt lgkmcnt(0)" ::: "memory");
    }

    __syncthreads();
    const __bf16* Wv = Wbf + 2 * (128 * 128);
    #pragma unroll
    for (int msub = 0; msub < 8; ++msub) {
        f32x4 acc = {0.f, 0.f, 0.f, 0.f};
        #pragma unroll
        for (int ks = 0; ks < 4; ++ks) {
            bf16x8 wf = *(const bf16x8*)(Wv + (size_t)(msub * 16 + l16) * CC + ks * 32 + quad * 8);
            acc = __builtin_amdgcn_mfma_f32_16x16x32_bf16(wf, xf[ks], acc, 0, 0, 0);
        }
        #pragma unroll
        for (int r = 0; r < 4; ++r)
            tr[(msub * 16 + quad * 4 + r) * TR_V + wave * 16 + l16] = (__bf16)acc[r];
    }
    __syncthreads();
    #pragma unroll
    for (int i = 0; i < 4; ++i) {
        int t32 = i >> 1;
        int h16 = wave * 2 + (i & 1);
        const __bf16* p = &tr[(h16 * 16 + l16) * TR_V + t32 * 32 + quad * 8];
        uint2 lo = *(const uint2*)p;
        uint2 hi = *(const uint2*)(p + 4);
        uint4 v; v.x = lo.x; v.y = lo.y; v.z = hi.x; v.w = hi.y;
        __bf16* o = Vs + (((size_t)(b * 64 + t0 / 32 + t32) * 8 + h16) << 9) + lane * 8;
        *(uint4*)o = v;
    }
}

// ---------------------------------------------------------------------------
// Split-K flash attention, 128 q-rows/block, 32 q-rows/wave (2 subtiles).
// grid (SPB, 16), block 256 (4 waves). Static-max softmax (p = exp2(s-16)).
// Per-wave causal clamp skips fully-masked key tiles. All global loads are
// wave-uniform base + lane*16B (fragment-swizzled inputs).
// ---------------------------------------------------------------------------
#define S_LDS 76
#define EXP_BIAS 16.0f

__global__ __launch_bounds__(256) void attn_kernel(
    const __bf16* __restrict__ ws, float* __restrict__ po,
    float* __restrict__ outp, int G, int SPB, int direct)
{
    __shared__ __bf16 lds_p[4 * 32 * S_LDS];

    const int lane = threadIdx.x & 63;
    const int wave = threadIdx.x >> 6;
    const int quad = lane >> 4;
    const int l16  = lane & 15;
    const int lane8 = lane * 8;

    const int b = blockIdx.y;
    const int s = SPB - 1 - blockIdx.x;

    // slot -> (qt, seg)
    int acc = 0, qt = 0, seg = 0;
    for (int q = 0; q < NQT128; ++q) {
        int c = (2 * (q + 1) + G - 1) / G;
        if (s < acc + c) { qt = q; seg = s - acc; break; }
        acc += c;
    }
    const int kt0 = seg * G;
    int kt1 = 2 * (qt + 1);
    if (kt0 + G < kt1) kt1 = kt0 + G;

    const int q0 = qt * 128;
    const int qw = q0 + wave * 32;                 // wave's first q row
    int kt1w = (qw + 32 + 63) >> 6;                // wave causal clamp (excl)
    if (kt1w > kt1) kt1w = kt1;

    const __bf16* Qs = ws;
    const __bf16* Ks = ws + BTH;
    const __bf16* Vs = ws + 2 * BTH;

    bf16x8 qf[2][4];
    #pragma unroll
    for (int m = 0; m < 2; ++m)
        #pragma unroll
        for (int ks = 0; ks < 4; ++ks)
            qf[m][ks] = *(const bf16x8*)(Qs + (((size_t)(b * 128 + qt * 8 + wave * 2 + m) * 4 + ks) << 9) + lane8);

    float l_r[2][4];
    f32x4 o[2][8];
    #pragma unroll
    for (int m = 0; m < 2; ++m) {
        #pragma unroll
        for (int r = 0; r < 4; ++r) l_r[m][r] = 0.f;
        #pragma unroll
        for (int h8 = 0; h8 < 8; ++h8) o[m][h8] = (f32x4){0.f, 0.f, 0.f, 0.f};
    }

    __bf16* myP = lds_p + wave * 32 * S_LDS;

    // prologue: K fragments for first tile
    bf16x8 kf[4][4];
    #pragma unroll
    for (int nsub = 0; nsub < 4; ++nsub)
        #pragma unroll
        for (int ks = 0; ks < 4; ++ks)
            kf[nsub][ks] = *(const bf16x8*)(Ks + (((size_t)(b * 128 + kt0 * 4 + nsub) * 4 + ks) << 9) + lane8);

    for (int kt = kt0; kt < kt1w; ++kt) {
        const int k0 = kt * 64;

        // V half 0 (h8 = 0..3, both 32-key chunks) issued early
        bf16x8 va[4], vb[4];
        #pragma unroll
        for (int h8 = 0; h8 < 4; ++h8) {
            va[h8] = *(const bf16x8*)(Vs + (((size_t)(b * 64 + kt * 2 + 0) * 8 + h8) << 9) + lane8);
            vb[h8] = *(const bf16x8*)(Vs + (((size_t)(b * 64 + kt * 2 + 1) * 8 + h8) << 9) + lane8);
        }

        // S = Q K^T for both subtiles (independent chains)
        f32x4 s2[2][4];
        #pragma unroll
        for (int m = 0; m < 2; ++m)
            #pragma unroll
            for (int nsub = 0; nsub < 4; ++nsub) {
                f32x4 a2 = {0.f, 0.f, 0.f, 0.f};
                #pragma unroll
                for (int ks = 0; ks < 4; ++ks)
                    a2 = __builtin_amdgcn_mfma_f32_16x16x32_bf16(qf[m][ks], kf[nsub][ks], a2, 0, 0, 0);
                s2[m][nsub] = a2;
            }

        // prefetch next K tile in place
        const int ktn = (kt + 1 < kt1w) ? (kt + 1) : kt;
        #pragma unroll
        for (int nsub = 0; nsub < 4; ++nsub)
            #pragma unroll
            for (int ks = 0; ks < 4; ++ks)
                kf[nsub][ks] = *(const bf16x8*)(Ks + (((size_t)(b * 128 + ktn * 4 + nsub) * 4 + ks) << 9) + lane8);

        // mask + exp2 + lane-local l + LDS write
        #pragma unroll
        for (int m = 0; m < 2; ++m) {
            const int qr0m = qw + m * 16;
            if (k0 + 63 > qr0m) {
                #pragma unroll
                for (int nsub = 0; nsub < 4; ++nsub) {
                    int key = k0 + nsub * 16 + l16;
                    #pragma unroll
                    for (int r = 0; r < 4; ++r) {
                        int rowq = qr0m + quad * 4 + r;
                        if (key > rowq) s2[m][nsub][r] = -3e38f;
                    }
                }
            }
            #pragma unroll
            for (int nsub = 0; nsub < 4; ++nsub) {
                #pragma unroll
                for (int r = 0; r < 4; ++r) {
                    float p = __builtin_amdgcn_exp2f(s2[m][nsub][r] - EXP_BIAS);
                    l_r[m][r] += p;
                    myP[(m * 16 + quad * 4 + r) * S_LDS + nsub * 16 + l16] = (__bf16)p;
                }
            }
        }
        asm volatile("s_waitcnt lgkmcnt(0)" ::: "memory");

        // P: C-layout -> A-layout for both subtiles
        bf16x8 pf[2][2];
        #pragma unroll
        for (int m = 0; m < 2; ++m)
            #pragma unroll
            for (int ks2 = 0; ks2 < 2; ++ks2) {
                union { bf16x8 v; uint2 h[2]; } u;
                const char* base = (const char*)myP + (size_t)(m * 16 + l16) * (S_LDS * 2) + ks2 * 64 + quad * 16;
                u.h[0] = *(const uint2*)base;
                u.h[1] = *(const uint2*)(base + 8);
                pf[m][ks2] = u.v;
            }

        // O += P V
        #pragma unroll
        for (int h8 = 0; h8 < 4; ++h8)
            #pragma unroll
            for (int m = 0; m < 2; ++m) {
                o[m][h8] = __builtin_amdgcn_mfma_f32_16x16x32_bf16(pf[m][0], va[h8], o[m][h8], 0, 0, 0);
                o[m][h8] = __builtin_amdgcn_mfma_f32_16x16x32_bf16(pf[m][1], vb[h8], o[m][h8], 0, 0, 0);
            }
        #pragma unroll
        for (int h8 = 4; h8 < 8; ++h8) {
            bf16x8 v0 = *(const bf16x8*)(Vs + (((size_t)(b * 64 + kt * 2 + 0) * 8 + h8) << 9) + lane8);
            bf16x8 v1 = *(const bf16x8*)(Vs + (((size_t)(b * 64 + kt * 2 + 1) * 8 + h8) << 9) + lane8);
            #pragma unroll
            for (int m = 0; m < 2; ++m) {
                o[m][h8] = __builtin_amdgcn_mfma_f32_16x16x32_bf16(pf[m][0], v0, o[m][h8], 0, 0, 0);
                o[m][h8] = __builtin_amdgcn_mfma_f32_16x16x32_bf16(pf[m][1], v1, o[m][h8], 0, 0, 0);
            }
        }
    }

    // l reduction across the 16-lane row group
    #pragma unroll
    for (int m = 0; m < 2; ++m)
        #pragma unroll
        for (int r = 0; r < 4; ++r)
            #pragma unroll
            for (int j = 1; j <= 8; j <<= 1)
                l_r[m][r] += __shfl_xor(l_r[m][r], j, 64);

    if (direct) {
        #pragma unroll
        for (int m = 0; m < 2; ++m) {
            float inv[4];
            #pragma unroll
            for (int r = 0; r < 4; ++r) inv[r] = 1.0f / l_r[m][r];
            #pragma unroll
            for (int h8 = 0; h8 < 8; ++h8)
                #pragma unroll
                for (int r = 0; r < 4; ++r)
                    outp[(size_t)(b * TT + qw + m * 16 + quad * 4 + r) * HH + h8 * 16 + l16] = o[m][h8][r] * inv[r];
        }
    } else {
        float* slot = po + (size_t)(b * SPB + s) * SLOT_FLOATS;
        #pragma unroll
        for (int m = 0; m < 2; ++m) {
            #pragma unroll
            for (int h8 = 0; h8 < 8; ++h8)
                #pragma unroll
                for (int r = 0; r < 4; ++r)
                    slot[(size_t)(wave * 32 + m * 16 + quad * 4 + r) * HH + h8 * 16 + l16] = o[m][h8][r];
            if (l16 == 0) {
                #pragma unroll
                for (int r = 0; r < 4; ++r)
                    slot[128 * 128 + wave * 32 + m * 16 + quad * 4 + r] = l_r[m][r];
            }
        }
    }
}

// ---------------------------------------------------------------------------
// Reduce: sum partial (o, l) over segments, normalize.
// grid (NQT128*4, 16), block 256. Each block: 32 rows x 128 cols.
// sg is the OUTER loop -> 4 independent float4 accumulators per thread (MLP).
// ---------------------------------------------------------------------------
__global__ __launch_bounds__(256) void reduce_kernel(
    const float* __restrict__ po, float* __restrict__ outp, int G, int SPB)
{
    __shared__ float lsum[32];
    const int qt  = blockIdx.x >> 2;
    const int qtr = blockIdx.x & 3;
    const int b   = blockIdx.y;
    const int tid = threadIdx.x;

    int acc = 0;
    for (int qq = 0; qq < qt; ++qq) acc += (2 * (qq + 1) + G - 1) / G;
    const int segs = (2 * (qt + 1) + G - 1) / G;
    const float* base = po + (size_t)(b * SPB + acc) * SLOT_FLOATS;
    const int r0 = qtr * 32;                  // first row of this block's chunk

    if (tid < 32) {
        float v = 0.f;
        for (int sg = 0; sg < segs; ++sg)
            v += base[(size_t)sg * SLOT_FLOATS + 128 * 128 + r0 + tid];
        lsum[tid] = v;
    }
    __syncthreads();

    const int f4c  = tid & 31;                // float4 column (0..31)
    const int rowg = tid >> 5;                // 0..7
    float4 a[4];
    #pragma unroll
    for (int p = 0; p < 4; ++p) a[p] = (float4){0.f, 0.f, 0.f, 0.f};

    for (int sg = 0; sg < segs; ++sg) {
        const float* sb = base + (size_t)sg * SLOT_FLOATS;
        #pragma unroll
        for (int p = 0; p < 4; ++p) {
            int row = r0 + p * 8 + rowg;
            float4 v = *(const float4*)(sb + (size_t)row * 128 + f4c * 4);
            a[p].x += v.x; a[p].y += v.y; a[p].z += v.z; a[p].w += v.w;
        }
    }

    #pragma unroll
    for (int p = 0; p < 4; ++p) {
        int row = r0 + p * 8 + rowg;
        float inv = 1.0f / lsum[p * 8 + rowg];
        float4 o4 = {a[p].x * inv, a[p].y * inv, a[p].z * inv, a[p].w * inv};
        *(float4*)(outp + (size_t)(b * TT + qt * 128 + row) * HH + f4c * 4) = o4;
    }
}

extern "C" void kernel_launch(void* const* d_in, const int* in_sizes, int n_in,
                              void* d_out, int out_size, void* d_ws, size_t ws_size,
                              hipStream_t stream)
{
    const float* x  = (const float*)d_in[0];
    const float* Wq = (const float*)d_in[1];
    const float* Wk = (const float*)d_in[2];
    const float* Wv = (const float*)d_in[3];
    __bf16* ws = (__bf16*)d_ws;
    float* out = (float*)d_out;
    float* po  = (float*)((char*)d_ws + PARTIAL_OFF_BYTES);

    int G = 0, SPB = 0, direct = 1;
    const int cand[3] = {6, 8, 16};
    for (int ci = 0; ci < 3; ++ci) {
        int g = cand[ci], spb = 0;
        for (int q = 0; q < NQT128; ++q) spb += (2 * (q + 1) + g - 1) / g;
        size_t need = PARTIAL_OFF_BYTES + (size_t)spb * BB * SLOT_FLOATS * 4;
        if (need <= ws_size) { G = g; SPB = spb; direct = 0; break; }
    }
    if (direct) { G = 2 * NQT128; SPB = NQT128; }   // one segment per qtile

    wcvt_kernel<<<192, 256, 0, stream>>>(Wq, Wk, Wv, ws + WBF_OFF);
    proj_kernel<<<512, 256, 0, stream>>>(x, ws);
    dim3 agrid(SPB, BB);
    attn_kernel<<<agrid, 256, 0, stream>>>(ws, po, out, G, SPB, direct);
    if (!direct) {
        dim3 rgrid(NQT128 * 4, BB);
        reduce_kernel<<<rgrid, 256, 0, stream>>>(po, out, G, SPB);
    }
}

// Round 7
// 149.999 us; speedup vs baseline: 1.9848x; 1.1742x over previous
//
#include <hip/hip_runtime.h>
#include <hip/hip_bf16.h>

// Problem constants
#define BB 16
#define TT 2048
#define CC 128
#define HH 128
#define NQT128 16          // q tiles of 128 rows

typedef __bf16 bf16x8 __attribute__((ext_vector_type(8)));
typedef float  f32x4  __attribute__((ext_vector_type(4)));

// ws layout (bf16 elems unless noted):
//   Qs  [b][tt16 128][ks 4][lane 64][j 8]   (exp2-domain scale folded)
//   Ks  [b][tt16 128][ks 4][lane 64][j 8]   (one 64-key tile = 16 KB contig)
//   Vs  [b][t32 64][h16 8][lane 64][j 8]    (one 64-key tile = 16 KB contig)
//   Wbf 3*128*128  (Wq pre-scaled)
//   partials (float): slots of [128*128 o + 128 l]
#define BTH       ((size_t)BB * TT * HH)
#define WBF_OFF   (3 * BTH)
#define PARTIAL_OFF_BYTES (3 * BTH * 2 + 3 * 128 * 128 * 2)
#define SLOT_FLOATS (128 * 128 + 128)     // 16512

static __device__ __forceinline__ bf16x8 load_cvt8(const float* __restrict__ p) {
    float4 a = *(const float4*)p;
    float4 b = *(const float4*)(p + 4);
    bf16x8 r;
    r[0] = (__bf16)a.x; r[1] = (__bf16)a.y; r[2] = (__bf16)a.z; r[3] = (__bf16)a.w;
    r[4] = (__bf16)b.x; r[5] = (__bf16)b.y; r[6] = (__bf16)b.z; r[7] = (__bf16)b.w;
    return r;
}

// async global->LDS, 16 B/lane: data lands at lds_base + lane*16
static __device__ __forceinline__ void load_lds16(const void* g, void* l) {
    __builtin_amdgcn_global_load_lds(
        (const __attribute__((address_space(1))) unsigned int*)g,
        (__attribute__((address_space(3))) unsigned int*)l, 16, 0, 0);
}

// ---------------------------------------------------------------------------
// W pre-convert: fp32 -> bf16, Wq scaled by C^-0.5 * log2e.
// ---------------------------------------------------------------------------
__global__ __launch_bounds__(256) void wcvt_kernel(
    const float* __restrict__ Wq, const float* __restrict__ Wk,
    const float* __restrict__ Wv, __bf16* __restrict__ wbf)
{
    int idx = blockIdx.x * 256 + threadIdx.x;          // < 49152
    int m = idx >> 14;
    int e = idx & 16383;
    const float* src = (m == 0) ? Wq : (m == 1) ? Wk : Wv;
    float sc = (m == 0) ? (0.08838834764831845f * 1.4426950408889634f) : 1.0f;
    wbf[idx] = (__bf16)(src[e] * sc);
}

// ---------------------------------------------------------------------------
// Projection with fragment-swizzled output. grid 512, block 256 (4 waves).
// ---------------------------------------------------------------------------
#define TR_QK 132
#define TR_V  68

__global__ __launch_bounds__(256) void proj_kernel(
    const float* __restrict__ x, __bf16* __restrict__ ws)
{
    __shared__ __bf16 tr[128 * TR_V];

    const int lane = threadIdx.x & 63;
    const int wave = threadIdx.x >> 6;
    const int quad = lane >> 4;
    const int l16  = lane & 15;
    const int m0 = blockIdx.x * 64;
    const int b  = m0 / TT;
    const int t0 = m0 % TT;

    const __bf16* Wbf = ws + WBF_OFF;
    __bf16* Qs = ws;
    __bf16* Ks = ws + BTH;
    __bf16* Vs = ws + 2 * BTH;

    bf16x8 xf[4];
    #pragma unroll
    for (int ks = 0; ks < 4; ++ks)
        xf[ks] = load_cvt8(x + (size_t)(m0 + wave * 16 + l16) * CC + ks * 32 + quad * 8);

    #pragma unroll
    for (int which = 0; which < 2; ++which) {
        const __bf16* Wb = Wbf + (size_t)which * (128 * 128);
        __bf16* dst = which ? Ks : Qs;
        #pragma unroll
        for (int nt = 0; nt < 8; ++nt) {
            f32x4 acc = {0.f, 0.f, 0.f, 0.f};
            #pragma unroll
            for (int ks = 0; ks < 4; ++ks) {
                bf16x8 wf = *(const bf16x8*)(Wb + (size_t)(nt * 16 + l16) * CC + ks * 32 + quad * 8);
                acc = __builtin_amdgcn_mfma_f32_16x16x32_bf16(xf[ks], wf, acc, 0, 0, 0);
            }
            #pragma unroll
            for (int r = 0; r < 4; ++r)
                tr[(wave * 16 + quad * 4 + r) * TR_QK + nt * 16 + l16] = (__bf16)acc[r];
        }
        asm volatile("s_waitcnt lgkmcnt(0)" ::: "memory");
        #pragma unroll
        for (int ks = 0; ks < 4; ++ks) {
            const __bf16* p = &tr[(wave * 16 + l16) * TR_QK + ks * 32 + quad * 8];
            uint2 lo = *(const uint2*)p;
            uint2 hi = *(const uint2*)(p + 4);
            uint4 v; v.x = lo.x; v.y = lo.y; v.z = hi.x; v.w = hi.y;
            __bf16* o = dst + (((size_t)(b * 128 + t0 / 16 + wave) * 4 + ks) << 9) + lane * 8;
            *(uint4*)o = v;
        }
        asm volatile("s_waitcnt lgkmcnt(0)" ::: "memory");
    }

    __syncthreads();
    const __bf16* Wv = Wbf + 2 * (128 * 128);
    #pragma unroll
    for (int msub = 0; msub < 8; ++msub) {
        f32x4 acc = {0.f, 0.f, 0.f, 0.f};
        #pragma unroll
        for (int ks = 0; ks < 4; ++ks) {
            bf16x8 wf = *(const bf16x8*)(Wv + (size_t)(msub * 16 + l16) * CC + ks * 32 + quad * 8);
            acc = __builtin_amdgcn_mfma_f32_16x16x32_bf16(wf, xf[ks], acc, 0, 0, 0);
        }
        #pragma unroll
        for (int r = 0; r < 4; ++r)
            tr[(msub * 16 + quad * 4 + r) * TR_V + wave * 16 + l16] = (__bf16)acc[r];
    }
    __syncthreads();
    #pragma unroll
    for (int i = 0; i < 4; ++i) {
        int t32 = i >> 1;
        int h16 = wave * 2 + (i & 1);
        const __bf16* p = &tr[(h16 * 16 + l16) * TR_V + t32 * 32 + quad * 8];
        uint2 lo = *(const uint2*)p;
        uint2 hi = *(const uint2*)(p + 4);
        uint4 v; v.x = lo.x; v.y = lo.y; v.z = hi.x; v.w = hi.y;
        __bf16* o = Vs + (((size_t)(b * 64 + t0 / 32 + t32) * 8 + h16) << 9) + lane * 8;
        *(uint4*)o = v;
    }
}

// ---------------------------------------------------------------------------
// Split-K flash attention, 128 q-rows/block, 32 q-rows/wave (2 subtiles).
// 1D grid (SPB*16). XCD-aware decode: b = (lin&7)*2 + ((lin>>3)&1) clusters
// each batch's blocks onto one XCD so its 2 MB K/V working set stays in the
// 4 MB XCD-L2. K+V tiles staged once per block into LDS via global_load_lds
// (16B width); waves ds_read_b128 fragments. Static-max softmax exp2(s-16).
// ---------------------------------------------------------------------------
#define S_LDS 76
#define EXP_BIAS 16.0f

__global__ __launch_bounds__(256) void attn_kernel(
    const __bf16* __restrict__ ws, float* __restrict__ po,
    float* __restrict__ outp, int G, int SPB, int direct)
{
    __shared__ __bf16 ldsK[8192];               // 16 KB: one K tile, frag order
    __shared__ __bf16 ldsV[8192];               // 16 KB: one V tile, frag order
    __shared__ __bf16 lds_p[4 * 32 * S_LDS];    // P staging (wave-private rows)

    const int lane = threadIdx.x & 63;
    const int wave = threadIdx.x >> 6;
    const int quad = lane >> 4;
    const int l16  = lane & 15;
    const int lane8 = lane * 8;

    const int lin = blockIdx.x;
    const int b  = (lin & 7) * 2 + ((lin >> 3) & 1);   // XCD-clustered batch
    const int s  = SPB - 1 - (lin >> 4);               // heavy slots first

    // slot -> (qt, seg)
    int acc = 0, qt = 0, seg = 0;
    for (int q = 0; q < NQT128; ++q) {
        int c = (2 * (q + 1) + G - 1) / G;
        if (s < acc + c) { qt = q; seg = s - acc; break; }
        acc += c;
    }
    const int kt0 = seg * G;
    int kt1 = 2 * (qt + 1);
    if (kt0 + G < kt1) kt1 = kt0 + G;

    const int qw = qt * 128 + wave * 32;           // wave's first q row
    int kt1w = (qw + 32 + 63) >> 6;                // wave causal clamp (excl)
    if (kt1w > kt1) kt1w = kt1;

    const __bf16* Qs = ws;
    const __bf16* Ks = ws + BTH;
    const __bf16* Vs = ws + 2 * BTH;

    bf16x8 qf[2][4];
    #pragma unroll
    for (int m = 0; m < 2; ++m)
        #pragma unroll
        for (int ks = 0; ks < 4; ++ks)
            qf[m][ks] = *(const bf16x8*)(Qs + (((size_t)(b * 128 + qt * 8 + wave * 2 + m) * 4 + ks) << 9) + lane8);

    float l_r[2][4];
    f32x4 o[2][8];
    #pragma unroll
    for (int m = 0; m < 2; ++m) {
        #pragma unroll
        for (int r = 0; r < 4; ++r) l_r[m][r] = 0.f;
        #pragma unroll
        for (int h8 = 0; h8 < 8; ++h8) o[m][h8] = (f32x4){0.f, 0.f, 0.f, 0.f};
    }

    __bf16* myP = lds_p + wave * 32 * S_LDS;

    for (int kt = kt0; kt < kt1; ++kt) {
        // ---- cooperative staging: 32 x 1KB chunks (8 per wave) ------------
        const char* kbase = (const char*)(Ks + (((size_t)(b * 128 + kt * 4) * 4) << 9));
        const char* vbase = (const char*)(Vs + (((size_t)(b * 64 + kt * 2) * 8) << 9));
        #pragma unroll
        for (int i = 0; i < 8; ++i) {
            const int c = wave * 8 + i;            // wave-uniform chunk id
            const char* g = (c < 16) ? (kbase + c * 1024) : (vbase + (c - 16) * 1024);
            char* l = (c < 16) ? ((char*)ldsK + c * 1024) : ((char*)ldsV + (c - 16) * 1024);
            load_lds16(g + (size_t)lane * 16, l);
        }
        asm volatile("s_waitcnt vmcnt(0)" ::: "memory");
        __syncthreads();

        if (kt < kt1w) {
            const int k0 = kt * 64;

            // ---- S = Q K^T (K frags from LDS) -----------------------------
            f32x4 s2[2][4];
            #pragma unroll
            for (int nsub = 0; nsub < 4; ++nsub) {
                bf16x8 kfr[4];
                #pragma unroll
                for (int ks = 0; ks < 4; ++ks)
                    kfr[ks] = *(const bf16x8*)((const char*)ldsK + ((nsub * 4 + ks) << 10) + lane * 16);
                #pragma unroll
                for (int m = 0; m < 2; ++m) {
                    f32x4 a2 = {0.f, 0.f, 0.f, 0.f};
                    #pragma unroll
                    for (int ks = 0; ks < 4; ++ks)
                        a2 = __builtin_amdgcn_mfma_f32_16x16x32_bf16(qf[m][ks], kfr[ks], a2, 0, 0, 0);
                    s2[m][nsub] = a2;
                }
            }

            // ---- mask + exp2 + lane-local l + P write ---------------------
            #pragma unroll
            for (int m = 0; m < 2; ++m) {
                const int qr0m = qw + m * 16;
                if (k0 + 63 > qr0m) {
                    #pragma unroll
                    for (int nsub = 0; nsub < 4; ++nsub) {
                        int key = k0 + nsub * 16 + l16;
                        #pragma unroll
                        for (int r = 0; r < 4; ++r) {
                            int rowq = qr0m + quad * 4 + r;
                            if (key > rowq) s2[m][nsub][r] = -3e38f;
                        }
                    }
                }
                #pragma unroll
                for (int nsub = 0; nsub < 4; ++nsub) {
                    #pragma unroll
                    for (int r = 0; r < 4; ++r) {
                        float p = __builtin_amdgcn_exp2f(s2[m][nsub][r] - EXP_BIAS);
                        l_r[m][r] += p;
                        myP[(m * 16 + quad * 4 + r) * S_LDS + nsub * 16 + l16] = (__bf16)p;
                    }
                }
            }
            asm volatile("s_waitcnt lgkmcnt(0)" ::: "memory");

            // ---- P: C-layout -> A-layout ----------------------------------
            bf16x8 pf[2][2];
            #pragma unroll
            for (int m = 0; m < 2; ++m)
                #pragma unroll
                for (int ks2 = 0; ks2 < 2; ++ks2) {
                    union { bf16x8 v; uint2 h[2]; } u;
                    const char* base = (const char*)myP + (size_t)(m * 16 + l16) * (S_LDS * 2) + ks2 * 64 + quad * 16;
                    u.h[0] = *(const uint2*)base;
                    u.h[1] = *(const uint2*)(base + 8);
                    pf[m][ks2] = u.v;
                }

            // ---- O += P V (V frags from LDS) ------------------------------
            #pragma unroll
            for (int h8 = 0; h8 < 8; ++h8) {
                bf16x8 v0 = *(const bf16x8*)((const char*)ldsV + ((0 * 8 + h8) << 10) + lane * 16);
                bf16x8 v1 = *(const bf16x8*)((const char*)ldsV + ((1 * 8 + h8) << 10) + lane * 16);
                #pragma unroll
                for (int m = 0; m < 2; ++m) {
                    o[m][h8] = __builtin_amdgcn_mfma_f32_16x16x32_bf16(pf[m][0], v0, o[m][h8], 0, 0, 0);
                    o[m][h8] = __builtin_amdgcn_mfma_f32_16x16x32_bf16(pf[m][1], v1, o[m][h8], 0, 0, 0);
                }
            }
        }
        __syncthreads();   // all waves done reading ldsK/ldsV before next stage
    }

    // l reduction across the 16-lane row group
    #pragma unroll
    for (int m = 0; m < 2; ++m)
        #pragma unroll
        for (int r = 0; r < 4; ++r)
            #pragma unroll
            for (int j = 1; j <= 8; j <<= 1)
                l_r[m][r] += __shfl_xor(l_r[m][r], j, 64);

    if (direct) {
        #pragma unroll
        for (int m = 0; m < 2; ++m) {
            float inv[4];
            #pragma unroll
            for (int r = 0; r < 4; ++r) inv[r] = 1.0f / l_r[m][r];
            #pragma unroll
            for (int h8 = 0; h8 < 8; ++h8)
                #pragma unroll
                for (int r = 0; r < 4; ++r)
                    outp[(size_t)(b * TT + qw + m * 16 + quad * 4 + r) * HH + h8 * 16 + l16] = o[m][h8][r] * inv[r];
        }
    } else {
        float* slot = po + (size_t)(b * SPB + s) * SLOT_FLOATS;
        #pragma unroll
        for (int m = 0; m < 2; ++m) {
            #pragma unroll
            for (int h8 = 0; h8 < 8; ++h8)
                #pragma unroll
                for (int r = 0; r < 4; ++r)
                    slot[(size_t)(wave * 32 + m * 16 + quad * 4 + r) * HH + h8 * 16 + l16] = o[m][h8][r];
            if (l16 == 0) {
                #pragma unroll
                for (int r = 0; r < 4; ++r)
                    slot[128 * 128 + wave * 32 + m * 16 + quad * 4 + r] = l_r[m][r];
            }
        }
    }
}

// ---------------------------------------------------------------------------
// Reduce: sum partial (o, l) over segments, normalize.
// grid (NQT128*4, 16), block 256. Each block: 32 rows x 128 cols.
// sg outer loop -> 4 independent float4 accumulators per thread (MLP).
// ---------------------------------------------------------------------------
__global__ __launch_bounds__(256) void reduce_kernel(
    const float* __restrict__ po, float* __restrict__ outp, int G, int SPB)
{
    __shared__ float lsum[32];
    const int qt  = blockIdx.x >> 2;
    const int qtr = blockIdx.x & 3;
    const int b   = blockIdx.y;
    const int tid = threadIdx.x;

    int acc = 0;
    for (int qq = 0; qq < qt; ++qq) acc += (2 * (qq + 1) + G - 1) / G;
    const int segs = (2 * (qt + 1) + G - 1) / G;
    const float* base = po + (size_t)(b * SPB + acc) * SLOT_FLOATS;
    const int r0 = qtr * 32;

    if (tid < 32) {
        float v = 0.f;
        for (int sg = 0; sg < segs; ++sg)
            v += base[(size_t)sg * SLOT_FLOATS + 128 * 128 + r0 + tid];
        lsum[tid] = v;
    }
    __syncthreads();

    const int f4c  = tid & 31;
    const int rowg = tid >> 5;
    float4 a[4];
    #pragma unroll
    for (int p = 0; p < 4; ++p) a[p] = (float4){0.f, 0.f, 0.f, 0.f};

    for (int sg = 0; sg < segs; ++sg) {
        const float* sb = base + (size_t)sg * SLOT_FLOATS;
        #pragma unroll
        for (int p = 0; p < 4; ++p) {
            int row = r0 + p * 8 + rowg;
            float4 v = *(const float4*)(sb + (size_t)row * 128 + f4c * 4);
            a[p].x += v.x; a[p].y += v.y; a[p].z += v.z; a[p].w += v.w;
        }
    }

    #pragma unroll
    for (int p = 0; p < 4; ++p) {
        int row = r0 + p * 8 + rowg;
        float inv = 1.0f / lsum[p * 8 + rowg];
        float4 o4 = {a[p].x * inv, a[p].y * inv, a[p].z * inv, a[p].w * inv};
        *(float4*)(outp + (size_t)(b * TT + qt * 128 + row) * HH + f4c * 4) = o4;
    }
}

extern "C" void kernel_launch(void* const* d_in, const int* in_sizes, int n_in,
                              void* d_out, int out_size, void* d_ws, size_t ws_size,
                              hipStream_t stream)
{
    const float* x  = (const float*)d_in[0];
    const float* Wq = (const float*)d_in[1];
    const float* Wk = (const float*)d_in[2];
    const float* Wv = (const float*)d_in[3];
    __bf16* ws = (__bf16*)d_ws;
    float* out = (float*)d_out;
    float* po  = (float*)((char*)d_ws + PARTIAL_OFF_BYTES);

    int G = 0, SPB = 0, direct = 1;
    const int cand[3] = {6, 8, 16};
    for (int ci = 0; ci < 3; ++ci) {
        int g = cand[ci], spb = 0;
        for (int q = 0; q < NQT128; ++q) spb += (2 * (q + 1) + g - 1) / g;
        size_t need = PARTIAL_OFF_BYTES + (size_t)spb * BB * SLOT_FLOATS * 4;
        if (need <= ws_size) { G = g; SPB = spb; direct = 0; break; }
    }
    if (direct) { G = 2 * NQT128; SPB = NQT128; }   // one segment per qtile

    wcvt_kernel<<<192, 256, 0, stream>>>(Wq, Wk, Wv, ws + WBF_OFF);
    proj_kernel<<<512, 256, 0, stream>>>(x, ws);
    attn_kernel<<<SPB * 16, 256, 0, stream>>>(ws, po, out, G, SPB, direct);
    if (!direct) {
        dim3 rgrid(NQT128 * 4, BB);
        reduce_kernel<<<rgrid, 256, 0, stream>>>(po, out, G, SPB);
    }
}